// Round 1
// baseline (224.608 us; speedup 1.0000x reference)
//
#include <hip/hip_runtime.h>
#include <stdint.h>

#define HW   65536
#define IMG  256
#define NB   4
#define NC   64
#define NA   32

// ---------- helpers ----------
__device__ __forceinline__ unsigned short f2bf(float x) {
  unsigned u = __float_as_uint(x);
  u += 0x7FFFu + ((u >> 16) & 1u);      // RNE to bf16
  return (unsigned short)(u >> 16);
}
__device__ __forceinline__ float bflo(unsigned u) { return __uint_as_float(u << 16); }
__device__ __forceinline__ float bfhi(unsigned u) { return __uint_as_float(u & 0xFFFF0000u); }

// ---------- weight transpose: wT[((i*2+s)*64 + c)*32 + o] = w_s[i][o][c] ----------
__global__ void prep_wT(const float* __restrict__ qw, const float* __restrict__ kw,
                        float* __restrict__ wT) {
  for (int idx = threadIdx.x; idx < 3 * 2 * NC * NA; idx += 256) {
    int o = idx & 31;
    int c = (idx >> 5) & 63;
    int s = (idx >> 11) & 1;
    int i = idx >> 12;
    const float* w = s ? kw : qw;
    wT[idx] = w[(i * NA + o) * NC + c];
  }
}

// ---------- per-slice global min/max of kappa (uint-ordered; kappa >= 0) ----------
__global__ __launch_bounds__(256) void minmax_k(const float* __restrict__ kappa,
                                                unsigned* __restrict__ mm) {
  const int i = blockIdx.y;
  const unsigned* ku = (const unsigned*)kappa;
  unsigned lo = 0xFFFFFFFFu, hi = 0u;
  for (int idx = blockIdx.x * 256 + threadIdx.x; idx < NB * HW; idx += gridDim.x * 256) {
    int b = idx >> 16, p = idx & (HW - 1);
    unsigned v = ku[((size_t)(b * 3 + i)) * HW + p];
    lo = min(lo, v); hi = max(hi, v);
  }
#pragma unroll
  for (int d = 32; d >= 1; d >>= 1) {
    lo = min(lo, (unsigned)__shfl_xor((int)lo, d, 64));
    hi = max(hi, (unsigned)__shfl_xor((int)hi, d, 64));
  }
  __shared__ unsigned slo[4], shi[4];
  if ((threadIdx.x & 63) == 0) { slo[threadIdx.x >> 6] = lo; shi[threadIdx.x >> 6] = hi; }
  __syncthreads();
  if (threadIdx.x == 0) {
    lo = min(min(slo[0], slo[1]), min(slo[2], slo[3]));
    hi = max(max(shi[0], shi[1]), max(shi[2], shi[3]));
    atomicMin(&mm[i], lo);
    atomicMax(&mm[i + 3], hi);
  }
}

// ---------- projection + L2-normalize -> bf16 qn/kn (pixel-major, 32ch) ----------
__global__ __launch_bounds__(256) void proj_k(const float* __restrict__ feat,
                                              const float* __restrict__ wTi,
                                              unsigned* __restrict__ qbuf,
                                              unsigned* __restrict__ kbuf) {
  const int idx = blockIdx.x * 256 + threadIdx.x;     // 0 .. NB*HW-1
  const int b = idx >> 16, p = idx & (HW - 1);
  const float* fb = feat + (size_t)b * NC * HW + p;

  float aq[NA], ak[NA];
#pragma unroll
  for (int o = 0; o < NA; ++o) { aq[o] = 0.f; ak[o] = 0.f; }

#pragma unroll 4
  for (int c = 0; c < NC; ++c) {
    float fc = fb[(size_t)c * HW];                    // coalesced across lanes
    const float* wq = wTi + c * NA;                   // wave-uniform -> s_load
    const float* wk = wTi + 2048 + c * NA;
#pragma unroll
    for (int o = 0; o < NA; ++o) {
      aq[o] = fmaf(fc, wq[o], aq[o]);
      ak[o] = fmaf(fc, wk[o], ak[o]);
    }
  }

  float ssq = 0.f, ssk = 0.f;
#pragma unroll
  for (int o = 0; o < NA; ++o) {
    ssq = fmaf(aq[o], aq[o], ssq);
    ssk = fmaf(ak[o], ak[o], ssk);
  }
  float iq = 1.0f / fmaxf(sqrtf(ssq), 1e-12f);        // matches x / max(||x||, eps)
  float ik = 1.0f / fmaxf(sqrtf(ssk), 1e-12f);

  unsigned* dq = qbuf + (size_t)idx * 16;
  unsigned* dk = kbuf + (size_t)idx * 16;
#pragma unroll
  for (int t = 0; t < 16; ++t) {
    dq[t] = (unsigned)f2bf(aq[2 * t] * iq) | ((unsigned)f2bf(aq[2 * t + 1] * iq) << 16);
    dk[t] = (unsigned)f2bf(ak[2 * t] * ik) | ((unsigned)f2bf(ak[2 * t + 1] * ik) << 16);
  }
}

// ---------- windowed cosine correlation + tau scaling ----------
template <int KS>
__global__ __launch_bounds__(256) void corr_k(const unsigned* __restrict__ qn,
                                              const unsigned* __restrict__ kn,
                                              const float* __restrict__ kappa,
                                              const unsigned* __restrict__ mm,
                                              const int i, float* __restrict__ out) {
  constexpr int P = KS / 2;
  constexpr int TX = 16 + 2 * P;
  constexpr int NPX = TX * TX;
  constexpr int KK = KS * KS;
  constexpr int LS = 17;                 // uints per pixel (odd -> bank-spread)
  __shared__ unsigned ksh[NPX * LS];

  const int b = blockIdx.z;
  const int y0 = blockIdx.y * 16, x0 = blockIdx.x * 16;
  const int tx = threadIdx.x, ty = threadIdx.y;
  const int tid = ty * 16 + tx;

  // stage kn tile + halo (bf16 raw), zero outside image (matches pad-after-normalize)
  for (int px = tid; px < NPX; px += 256) {
    int ry = px / TX;
    int gy = y0 - P + ry;
    int gx = x0 - P + (px - ry * TX);
    uint4 v0, v1, v2, v3;
    if ((unsigned)gy < (unsigned)IMG && (unsigned)gx < (unsigned)IMG) {
      const uint4* sp = (const uint4*)(kn + ((size_t)b * HW + gy * IMG + gx) * 16);
      v0 = sp[0]; v1 = sp[1]; v2 = sp[2]; v3 = sp[3];
    } else {
      v0 = make_uint4(0u, 0u, 0u, 0u); v1 = v0; v2 = v0; v3 = v0;
    }
    unsigned* d = ksh + px * LS;
    d[0] = v0.x;  d[1] = v0.y;  d[2] = v0.z;  d[3] = v0.w;
    d[4] = v1.x;  d[5] = v1.y;  d[6] = v1.z;  d[7] = v1.w;
    d[8] = v2.x;  d[9] = v2.y;  d[10] = v2.z; d[11] = v2.w;
    d[12] = v3.x; d[13] = v3.y; d[14] = v3.z; d[15] = v3.w;
  }

  // own-pixel qn -> 32 f32 regs
  const int y = y0 + ty, x = x0 + tx;
  const size_t pix = (size_t)b * HW + y * IMG + x;
  float q[NA];
  {
    const uint4* sp = (const uint4*)(qn + pix * 16);
    uint4 v0 = sp[0], v1 = sp[1], v2 = sp[2], v3 = sp[3];
    unsigned u[16] = {v0.x, v0.y, v0.z, v0.w, v1.x, v1.y, v1.z, v1.w,
                      v2.x, v2.y, v2.z, v2.w, v3.x, v3.y, v3.z, v3.w};
#pragma unroll
    for (int t = 0; t < 16; ++t) { q[2 * t] = bflo(u[t]); q[2 * t + 1] = bfhi(u[t]); }
  }

  // tau from global slice min/max
  float kap = kappa[((size_t)(b * 3 + i)) * HW + y * IMG + x];
  float kmin = __uint_as_float(mm[i]);
  float kmax = __uint_as_float(mm[i + 3]);
  float kapn = (kap - kmin) / (kmax - kmin + 1e-6f);
  float tau = fminf(fmaxf(0.5f - kapn * (0.5f - 0.03f), 0.03f), 0.5f);
  float scale = 1.0f / (tau + 1e-6f);

  __syncthreads();

  float* ob = out + (size_t)b * KK * HW + y * IMG + x;
#pragma unroll 1
  for (int dy = 0; dy < KS; ++dy) {
#pragma unroll
    for (int dx = 0; dx < KS; ++dx) {
      const unsigned* kr = ksh + ((ty + dy) * TX + (tx + dx)) * LS;
      float s = 0.f;
#pragma unroll
      for (int t = 0; t < 16; ++t) {
        unsigned u = kr[t];
        s = fmaf(q[2 * t], bflo(u), s);
        s = fmaf(q[2 * t + 1], bfhi(u), s);
      }
      ob[(size_t)(dy * KS + dx) * HW] = s * scale;
    }
  }
}

// ---------- launch ----------
extern "C" void kernel_launch(void* const* d_in, const int* in_sizes, int n_in,
                              void* d_out, int out_size, void* d_ws, size_t ws_size,
                              hipStream_t stream) {
  const float* feat  = (const float*)d_in[0];
  const float* kappa = (const float*)d_in[1];
  const float* qw    = (const float*)d_in[2];
  const float* kw    = (const float*)d_in[3];
  float* out = (float*)d_out;

  char* ws = (char*)d_ws;
  unsigned* mm = (unsigned*)ws;                      // 6 uints: min[3], max[3]
  float* wT = (float*)(ws + 64);                     // 12288 f32
  unsigned* qbuf = (unsigned*)(ws + 65536);          // NB*HW*16 uints (16.78 MB)
  unsigned* kbuf = qbuf + (size_t)NB * HW * 16;      // same size
  // total ws need: 65536 + 2*16*NB*HW*4 = ~33.6 MB

  hipMemsetAsync(mm, 0xFF, 12, stream);              // min init = UINT_MAX
  hipMemsetAsync((char*)mm + 12, 0x00, 12, stream);  // max init = 0

  hipLaunchKernelGGL(prep_wT, dim3(1), dim3(256), 0, stream, qw, kw, wT);
  hipLaunchKernelGGL(minmax_k, dim3(64, 3), dim3(256), 0, stream, kappa, mm);

  const size_t plane = (size_t)NB * HW;
  float* out0 = out;                  // k=3: 9 planes
  float* out1 = out0 + plane * 9;     // k=5: 25 planes
  float* out2 = out1 + plane * 25;    // k=7: 49 planes

  for (int i = 0; i < 3; ++i) {
    hipLaunchKernelGGL(proj_k, dim3(NB * HW / 256), dim3(256), 0, stream,
                       feat, wT + i * 4096, qbuf, kbuf);
    if (i == 0)
      hipLaunchKernelGGL(corr_k<3>, dim3(IMG / 16, IMG / 16, NB), dim3(16, 16), 0, stream,
                         qbuf, kbuf, kappa, mm, 0, out0);
    else if (i == 1)
      hipLaunchKernelGGL(corr_k<5>, dim3(IMG / 16, IMG / 16, NB), dim3(16, 16), 0, stream,
                         qbuf, kbuf, kappa, mm, 1, out1);
    else
      hipLaunchKernelGGL(corr_k<7>, dim3(IMG / 16, IMG / 16, NB), dim3(16, 16), 0, stream,
                         qbuf, kbuf, kappa, mm, 2, out2);
  }
}

// Round 2
// 149.588 us; speedup vs baseline: 1.5015x; 1.5015x over previous
//
#include <hip/hip_runtime.h>
#include <stdint.h>

#define HW   65536
#define IMG  256
#define NB   4
#define NC   64
#define NA   32

typedef __attribute__((ext_vector_type(8))) short short8v;
typedef __attribute__((ext_vector_type(4))) float f32x4;

// ---------- helpers ----------
__device__ __forceinline__ unsigned short f2bf(float x) {
  unsigned u = __float_as_uint(x);
  u += 0x7FFFu + ((u >> 16) & 1u);      // RNE to bf16
  return (unsigned short)(u >> 16);
}
__device__ __forceinline__ float bfval(unsigned short h) { return __uint_as_float((unsigned)h << 16); }
__device__ __forceinline__ float bflo(unsigned u) { return __uint_as_float(u << 16); }
__device__ __forceinline__ float bfhi(unsigned u) { return __uint_as_float(u & 0xFFFF0000u); }
__device__ __forceinline__ unsigned packbf(float a, float b) {
  return (unsigned)f2bf(a) | ((unsigned)f2bf(b) << 16);
}

// ---------- weight fragments in MFMA lane order ----------
// afrag[i(3)][mt(4)][ks(2)][h(2)][lane(64)][j(8)] bf16
// mt = s*2+m (s: 0=q 1=k); out o = (mt&1)*16 + (lane&15); ch = ks*32 + (lane>>4)*8 + j
__global__ void prep_afrag(const float* __restrict__ qw, const float* __restrict__ kw,
                           unsigned short* __restrict__ afrag) {
  int idx = blockIdx.x * 256 + threadIdx.x;
  if (idx >= 3 * 4 * 2 * 2 * 64 * 8) return;
  int j    = idx & 7;
  int lane = (idx >> 3) & 63;
  int h    = (idx >> 9) & 1;
  int ks   = (idx >> 10) & 1;
  int mt   = (idx >> 11) & 3;
  int i    = idx >> 13;
  int s = mt >> 1;
  int o = (mt & 1) * 16 + (lane & 15);
  int c = ks * 32 + (lane >> 4) * 8 + j;
  float v = (s ? kw : qw)[((size_t)i * NA + o) * NC + c];
  unsigned short hi = f2bf(v);
  afrag[idx] = h ? f2bf(v - bfval(hi)) : hi;
}

// ---------- per-slice global min/max of kappa (uint-ordered; kappa >= 0) ----------
__global__ __launch_bounds__(256) void minmax_k(const float* __restrict__ kappa,
                                                unsigned* __restrict__ mm) {
  const int i = blockIdx.y;
  const unsigned* ku = (const unsigned*)kappa;
  unsigned lo = 0xFFFFFFFFu, hi = 0u;
  for (int idx = blockIdx.x * 256 + threadIdx.x; idx < NB * HW; idx += gridDim.x * 256) {
    int b = idx >> 16, p = idx & (HW - 1);
    unsigned v = ku[((size_t)(b * 3 + i)) * HW + p];
    lo = min(lo, v); hi = max(hi, v);
  }
#pragma unroll
  for (int d = 32; d >= 1; d >>= 1) {
    lo = min(lo, (unsigned)__shfl_xor((int)lo, d, 64));
    hi = max(hi, (unsigned)__shfl_xor((int)hi, d, 64));
  }
  __shared__ unsigned slo[4], shi[4];
  if ((threadIdx.x & 63) == 0) { slo[threadIdx.x >> 6] = lo; shi[threadIdx.x >> 6] = hi; }
  __syncthreads();
  if (threadIdx.x == 0) {
    lo = min(min(slo[0], slo[1]), min(slo[2], slo[3]));
    hi = max(max(shi[0], shi[1]), max(shi[2], shi[3]));
    atomicMin(&mm[i], lo);
    atomicMax(&mm[i + 3], hi);
  }
}

// ---------- MFMA projection + L2-normalize -> bf16 qn/kn ----------
// GEMM: D[out=64, px] = W[64,64ch] * feat[64ch, px], hi/lo bf16 split (3 products).
// Block = 4 waves: wave = (s = w&1 q/k, phalf = w>>1). Wave covers 2 M-tiles x 64 px.
__global__ __launch_bounds__(256) void proj_mfma(const float* __restrict__ feat,
                                                 const unsigned short* __restrict__ afr,
                                                 unsigned* __restrict__ qbuf,
                                                 unsigned* __restrict__ kbuf) {
  const int t = blockIdx.x;
  const int b = t >> 9;                       // 512 tiles of 128 px per batch
  const int p0 = (t & 511) * 128;
  const int lane = threadIdx.x & 63;
  const int w = threadIdx.x >> 6;
  const int s = w & 1;
  const int pbase = p0 + (w >> 1) * 64;

  // A fragments (weights) in lane order: one 16B load each
  short8v ah[2][2], al[2][2];
#pragma unroll
  for (int m = 0; m < 2; ++m)
#pragma unroll
    for (int ks = 0; ks < 2; ++ks) {
      int mt = s * 2 + m;
      const unsigned short* base = afr + (size_t)((mt * 2 + ks) * 2) * 512 + lane * 8;
      ah[m][ks] = *(const short8v*)(base);
      al[m][ks] = *(const short8v*)(base + 512);
    }

  f32x4 acc[2][4];
#pragma unroll
  for (int m = 0; m < 2; ++m)
#pragma unroll
    for (int nt = 0; nt < 4; ++nt) acc[m][nt] = (f32x4){0.f, 0.f, 0.f, 0.f};

  const float* fb = feat + (size_t)b * NC * HW;
#pragma unroll
  for (int nt = 0; nt < 4; ++nt) {
    const int px = pbase + nt * 16 + (lane & 15);
#pragma unroll
    for (int ks = 0; ks < 2; ++ks) {
      const float* fp = fb + (size_t)(ks * 32 + (lane >> 4) * 8) * HW + px;
      float fv[8];
#pragma unroll
      for (int j = 0; j < 8; ++j) fv[j] = fp[(size_t)j * HW];   // 4x64B lines, coalesced
      short8v bh, bl;
#pragma unroll
      for (int j = 0; j < 8; ++j) {
        unsigned short h = f2bf(fv[j]);
        bh[j] = (short)h;
        bl[j] = (short)f2bf(fv[j] - bfval(h));
      }
#pragma unroll
      for (int m = 0; m < 2; ++m) {
        acc[m][nt] = __builtin_amdgcn_mfma_f32_16x16x32_bf16(ah[m][ks], bh, acc[m][nt], 0, 0, 0);
        acc[m][nt] = __builtin_amdgcn_mfma_f32_16x16x32_bf16(ah[m][ks], bl, acc[m][nt], 0, 0, 0);
        acc[m][nt] = __builtin_amdgcn_mfma_f32_16x16x32_bf16(al[m][ks], bh, acc[m][nt], 0, 0, 0);
      }
    }
  }

  // L2-normalize over 32 chs (rows of the 2 M-tiles), pack bf16, store
  unsigned* dstbuf = s ? kbuf : qbuf;
#pragma unroll
  for (int nt = 0; nt < 4; ++nt) {
    float ssq = 0.f;
#pragma unroll
    for (int m = 0; m < 2; ++m)
#pragma unroll
      for (int r = 0; r < 4; ++r) ssq = fmaf(acc[m][nt][r], acc[m][nt][r], ssq);
    ssq += __shfl_xor(ssq, 16, 64);
    ssq += __shfl_xor(ssq, 32, 64);
    float inv = 1.0f / fmaxf(sqrtf(ssq), 1e-12f);
    const int px = pbase + nt * 16 + (lane & 15);
    const size_t pix = (size_t)b * HW + px;
#pragma unroll
    for (int m = 0; m < 2; ++m) {
      int c0 = m * 16 + (lane >> 4) * 4;      // ch of reg 0 (multiple of 4)
      uint2 v;
      v.x = packbf(acc[m][nt][0] * inv, acc[m][nt][1] * inv);
      v.y = packbf(acc[m][nt][2] * inv, acc[m][nt][3] * inv);
      *(uint2*)(dstbuf + pix * 16 + (c0 >> 1)) = v;
    }
  }
}

// ---------- windowed cosine correlation + tau scaling ----------
template <int KS>
__global__ __launch_bounds__(256) void corr_k(const unsigned* __restrict__ qn,
                                              const unsigned* __restrict__ kn,
                                              const float* __restrict__ kappa,
                                              const unsigned* __restrict__ mm,
                                              const int i, float* __restrict__ out) {
  constexpr int P = KS / 2;
  constexpr int TX = 16 + 2 * P;
  constexpr int NPX = TX * TX;
  constexpr int KK = KS * KS;
  constexpr int LS = 17;                 // uints per pixel (odd -> bank-spread)
  __shared__ unsigned ksh[NPX * LS];

  const int b = blockIdx.z;
  const int y0 = blockIdx.y * 16, x0 = blockIdx.x * 16;
  const int tx = threadIdx.x, ty = threadIdx.y;
  const int tid = ty * 16 + tx;

  for (int px = tid; px < NPX; px += 256) {
    int ry = px / TX;
    int gy = y0 - P + ry;
    int gx = x0 - P + (px - ry * TX);
    uint4 v0, v1, v2, v3;
    if ((unsigned)gy < (unsigned)IMG && (unsigned)gx < (unsigned)IMG) {
      const uint4* sp = (const uint4*)(kn + ((size_t)b * HW + gy * IMG + gx) * 16);
      v0 = sp[0]; v1 = sp[1]; v2 = sp[2]; v3 = sp[3];
    } else {
      v0 = make_uint4(0u, 0u, 0u, 0u); v1 = v0; v2 = v0; v3 = v0;
    }
    unsigned* d = ksh + px * LS;
    d[0] = v0.x;  d[1] = v0.y;  d[2] = v0.z;  d[3] = v0.w;
    d[4] = v1.x;  d[5] = v1.y;  d[6] = v1.z;  d[7] = v1.w;
    d[8] = v2.x;  d[9] = v2.y;  d[10] = v2.z; d[11] = v2.w;
    d[12] = v3.x; d[13] = v3.y; d[14] = v3.z; d[15] = v3.w;
  }

  const int y = y0 + ty, x = x0 + tx;
  const size_t pix = (size_t)b * HW + y * IMG + x;
  float q[NA];
  {
    const uint4* sp = (const uint4*)(qn + pix * 16);
    uint4 v0 = sp[0], v1 = sp[1], v2 = sp[2], v3 = sp[3];
    unsigned u[16] = {v0.x, v0.y, v0.z, v0.w, v1.x, v1.y, v1.z, v1.w,
                      v2.x, v2.y, v2.z, v2.w, v3.x, v3.y, v3.z, v3.w};
#pragma unroll
    for (int t = 0; t < 16; ++t) { q[2 * t] = bflo(u[t]); q[2 * t + 1] = bfhi(u[t]); }
  }

  float kap = kappa[((size_t)(b * 3 + i)) * HW + y * IMG + x];
  float kmin = __uint_as_float(mm[i]);
  float kmax = __uint_as_float(mm[i + 3]);
  float kapn = (kap - kmin) / (kmax - kmin + 1e-6f);
  float tau = fminf(fmaxf(0.5f - kapn * (0.5f - 0.03f), 0.03f), 0.5f);
  float scale = 1.0f / (tau + 1e-6f);

  __syncthreads();

  float* ob = out + (size_t)b * KK * HW + y * IMG + x;
#pragma unroll 1
  for (int dy = 0; dy < KS; ++dy) {
#pragma unroll
    for (int dx = 0; dx < KS; ++dx) {
      const unsigned* kr = ksh + ((ty + dy) * TX + (tx + dx)) * LS;
      float s = 0.f;
#pragma unroll
      for (int t = 0; t < 16; ++t) {
        unsigned u = kr[t];
        s = fmaf(q[2 * t], bflo(u), s);
        s = fmaf(q[2 * t + 1], bfhi(u), s);
      }
      ob[(size_t)(dy * KS + dx) * HW] = s * scale;
    }
  }
}

// ---------- launch ----------
extern "C" void kernel_launch(void* const* d_in, const int* in_sizes, int n_in,
                              void* d_out, int out_size, void* d_ws, size_t ws_size,
                              hipStream_t stream) {
  const float* feat  = (const float*)d_in[0];
  const float* kappa = (const float*)d_in[1];
  const float* qw    = (const float*)d_in[2];
  const float* kw    = (const float*)d_in[3];
  float* out = (float*)d_out;

  char* ws = (char*)d_ws;
  unsigned* mm = (unsigned*)ws;                      // 6 uints: min[3], max[3]
  unsigned short* afrag = (unsigned short*)(ws + 64);// 24576 bf16 (49 KB)
  unsigned* qbuf = (unsigned*)(ws + 65536);          // NB*HW*16 uints (16.78 MB)
  unsigned* kbuf = qbuf + (size_t)NB * HW * 16;      // same size

  hipMemsetAsync(mm, 0xFF, 12, stream);              // min init = UINT_MAX
  hipMemsetAsync((char*)mm + 12, 0x00, 12, stream);  // max init = 0

  hipLaunchKernelGGL(prep_afrag, dim3(96), dim3(256), 0, stream, qw, kw, afrag);
  hipLaunchKernelGGL(minmax_k, dim3(64, 3), dim3(256), 0, stream, kappa, mm);

  const size_t plane = (size_t)NB * HW;
  float* out0 = out;                  // k=3: 9 planes
  float* out1 = out0 + plane * 9;     // k=5: 25 planes
  float* out2 = out1 + plane * 25;    // k=7: 49 planes

  for (int i = 0; i < 3; ++i) {
    hipLaunchKernelGGL(proj_mfma, dim3(NB * HW / 128), dim3(256), 0, stream,
                       feat, afrag + (size_t)i * 8192, qbuf, kbuf);
    if (i == 0)
      hipLaunchKernelGGL(corr_k<3>, dim3(IMG / 16, IMG / 16, NB), dim3(16, 16), 0, stream,
                         qbuf, kbuf, kappa, mm, 0, out0);
    else if (i == 1)
      hipLaunchKernelGGL(corr_k<5>, dim3(IMG / 16, IMG / 16, NB), dim3(16, 16), 0, stream,
                         qbuf, kbuf, kappa, mm, 1, out1);
    else
      hipLaunchKernelGGL(corr_k<7>, dim3(IMG / 16, IMG / 16, NB), dim3(16, 16), 0, stream,
                         qbuf, kbuf, kappa, mm, 2, out2);
  }
}

// Round 3
// 119.646 us; speedup vs baseline: 1.8773x; 1.2503x over previous
//
#include <hip/hip_runtime.h>
#include <stdint.h>

#define HW   65536
#define IMG  256
#define NB   4
#define NC   64
#define NA   32

typedef __attribute__((ext_vector_type(8))) short short8v;
typedef __attribute__((ext_vector_type(4))) float f32x4;

// ---------- helpers ----------
__device__ __forceinline__ unsigned short f2bf(float x) {
  unsigned u = __float_as_uint(x);
  u += 0x7FFFu + ((u >> 16) & 1u);      // RNE to bf16
  return (unsigned short)(u >> 16);
}
__device__ __forceinline__ float bfval(unsigned short h) { return __uint_as_float((unsigned)h << 16); }
__device__ __forceinline__ float bflo(unsigned u) { return __uint_as_float(u << 16); }
__device__ __forceinline__ float bfhi(unsigned u) { return __uint_as_float(u & 0xFFFF0000u); }
__device__ __forceinline__ unsigned packbf(float a, float b) {
  return (unsigned)f2bf(a) | ((unsigned)f2bf(b) << 16);
}

// ---------- weight fragments in MFMA lane order (+ mm init, replaces memsets) ----------
// afrag[i(3)][mt(4)][ks(2)][h(2)][lane(64)][j(8)] bf16
// mt = s*2+m (s: 0=q 1=k); out o = (mt&1)*16 + (lane&15); ch = ks*32 + (lane>>4)*8 + j
__global__ void prep_afrag(const float* __restrict__ qw, const float* __restrict__ kw,
                           unsigned short* __restrict__ afrag, unsigned* __restrict__ mm) {
  int idx = blockIdx.x * 256 + threadIdx.x;
  if (blockIdx.x == 0 && threadIdx.x < 6)
    mm[threadIdx.x] = (threadIdx.x < 3) ? 0xFFFFFFFFu : 0u;
  if (idx >= 3 * 4 * 2 * 2 * 64 * 8) return;
  int j    = idx & 7;
  int lane = (idx >> 3) & 63;
  int h    = (idx >> 9) & 1;
  int ks   = (idx >> 10) & 1;
  int mt   = (idx >> 11) & 3;
  int i    = idx >> 13;
  int s = mt >> 1;
  int o = (mt & 1) * 16 + (lane & 15);
  int c = ks * 32 + (lane >> 4) * 8 + j;
  float v = (s ? kw : qw)[((size_t)i * NA + o) * NC + c];
  unsigned short hi = f2bf(v);
  afrag[idx] = h ? f2bf(v - bfval(hi)) : hi;
}

// ---------- per-slice global min/max of kappa (uint-ordered; kappa >= 0) ----------
__global__ __launch_bounds__(256) void minmax_k(const float* __restrict__ kappa,
                                                unsigned* __restrict__ mm) {
  const int i = blockIdx.y;
  const unsigned* ku = (const unsigned*)kappa;
  unsigned lo = 0xFFFFFFFFu, hi = 0u;
  for (int idx = blockIdx.x * 256 + threadIdx.x; idx < NB * HW; idx += gridDim.x * 256) {
    int b = idx >> 16, p = idx & (HW - 1);
    unsigned v = ku[((size_t)(b * 3 + i)) * HW + p];
    lo = min(lo, v); hi = max(hi, v);
  }
#pragma unroll
  for (int d = 32; d >= 1; d >>= 1) {
    lo = min(lo, (unsigned)__shfl_xor((int)lo, d, 64));
    hi = max(hi, (unsigned)__shfl_xor((int)hi, d, 64));
  }
  __shared__ unsigned slo[4], shi[4];
  if ((threadIdx.x & 63) == 0) { slo[threadIdx.x >> 6] = lo; shi[threadIdx.x >> 6] = hi; }
  __syncthreads();
  if (threadIdx.x == 0) {
    lo = min(min(slo[0], slo[1]), min(slo[2], slo[3]));
    hi = max(max(shi[0], shi[1]), max(shi[2], shi[3]));
    atomicMin(&mm[i], lo);
    atomicMax(&mm[i + 3], hi);
  }
}

// ---------- fused MFMA projection (nsl slices) + L2-normalize -> bf16 qn/kn ----------
// GEMM per slice: D[out=64, px] = W[64,64ch] * feat[64ch, px], hi/lo bf16 split.
// Block = 4 waves: wave = (s = w&1 q/k, phalf = w>>1), covers 2 M-tiles x 64 px.
// B fragments (feat) built ONCE per wave; A fragments reloaded per slice (L1-hot).
__global__ __launch_bounds__(256) void proj_all(const float* __restrict__ feat,
                                                const unsigned short* __restrict__ afr,
                                                unsigned* __restrict__ qb,
                                                unsigned* __restrict__ kb,
                                                const int nsl, const int i0) {
  const int t = blockIdx.x;
  const int b = t >> 9;                       // 512 tiles of 128 px per batch
  const int p0 = (t & 511) * 128;
  const int lane = threadIdx.x & 63;
  const int w = threadIdx.x >> 6;
  const int s = w & 1;
  const int pbase = p0 + (w >> 1) * 64;

  // ---- build B (feat) fragments once: 4 n-tiles x 2 k-slices, hi/lo ----
  short8v bh[4][2], bl[4][2];
  const float* fb = feat + (size_t)b * NC * HW;
#pragma unroll
  for (int nt = 0; nt < 4; ++nt) {
    const int px = pbase + nt * 16 + (lane & 15);
#pragma unroll
    for (int ks = 0; ks < 2; ++ks) {
      const float* fp = fb + (size_t)(ks * 32 + (lane >> 4) * 8) * HW + px;
      float fv[8];
#pragma unroll
      for (int j = 0; j < 8; ++j) fv[j] = fp[(size_t)j * HW];   // 4x64B lines, coalesced
#pragma unroll
      for (int j = 0; j < 8; ++j) {
        unsigned short h = f2bf(fv[j]);
        bh[nt][ks][j] = (short)h;
        bl[nt][ks][j] = (short)f2bf(fv[j] - bfval(h));
      }
    }
  }

  unsigned* dstbuf0 = s ? kb : qb;

#pragma unroll 1
  for (int sl = 0; sl < nsl; ++sl) {
    const unsigned short* af = afr + (size_t)(i0 + sl) * 8192;

    // A fragments (weights): one 16B load each, L1-resident
    short8v ah[2][2], al[2][2];
#pragma unroll
    for (int m = 0; m < 2; ++m)
#pragma unroll
      for (int ks = 0; ks < 2; ++ks) {
        int mt = s * 2 + m;
        const unsigned short* base = af + (size_t)((mt * 2 + ks) * 2) * 512 + lane * 8;
        ah[m][ks] = *(const short8v*)(base);
        al[m][ks] = *(const short8v*)(base + 512);
      }

    f32x4 acc[2][4];
#pragma unroll
    for (int m = 0; m < 2; ++m)
#pragma unroll
      for (int nt = 0; nt < 4; ++nt) acc[m][nt] = (f32x4){0.f, 0.f, 0.f, 0.f};

#pragma unroll
    for (int nt = 0; nt < 4; ++nt)
#pragma unroll
      for (int ks = 0; ks < 2; ++ks)
#pragma unroll
        for (int m = 0; m < 2; ++m) {
          acc[m][nt] = __builtin_amdgcn_mfma_f32_16x16x32_bf16(ah[m][ks], bh[nt][ks], acc[m][nt], 0, 0, 0);
          acc[m][nt] = __builtin_amdgcn_mfma_f32_16x16x32_bf16(ah[m][ks], bl[nt][ks], acc[m][nt], 0, 0, 0);
          acc[m][nt] = __builtin_amdgcn_mfma_f32_16x16x32_bf16(al[m][ks], bh[nt][ks], acc[m][nt], 0, 0, 0);
        }

    // L2-normalize over the 32 chs of this wave's s, pack bf16, store
    unsigned* dstbuf = dstbuf0 + (size_t)sl * NB * HW * 16;
#pragma unroll
    for (int nt = 0; nt < 4; ++nt) {
      float ssq = 0.f;
#pragma unroll
      for (int m = 0; m < 2; ++m)
#pragma unroll
        for (int r = 0; r < 4; ++r) ssq = fmaf(acc[m][nt][r], acc[m][nt][r], ssq);
      ssq += __shfl_xor(ssq, 16, 64);
      ssq += __shfl_xor(ssq, 32, 64);
      float inv = 1.0f / fmaxf(sqrtf(ssq), 1e-12f);
      const int px = pbase + nt * 16 + (lane & 15);
      const size_t pix = (size_t)b * HW + px;
#pragma unroll
      for (int m = 0; m < 2; ++m) {
        int c0 = m * 16 + (lane >> 4) * 4;      // ch of reg 0 (multiple of 4)
        uint2 v;
        v.x = packbf(acc[m][nt][0] * inv, acc[m][nt][1] * inv);
        v.y = packbf(acc[m][nt][2] * inv, acc[m][nt][3] * inv);
        *(uint2*)(dstbuf + pix * 16 + (c0 >> 1)) = v;
      }
    }
  }
}

// ---------- windowed cosine correlation + tau scaling ----------
template <int KS>
__device__ __forceinline__ void corr_body(unsigned* __restrict__ ksh,
                                          const unsigned* __restrict__ qn,
                                          const unsigned* __restrict__ kn,
                                          const float* __restrict__ kappa,
                                          const unsigned* __restrict__ mm,
                                          const int i, const int b,
                                          float* __restrict__ out) {
  constexpr int P = KS / 2;
  constexpr int TX = 16 + 2 * P;
  constexpr int NPX = TX * TX;
  constexpr int KK = KS * KS;
  constexpr int LS = 17;                 // uints per pixel (odd -> bank-spread)

  const int y0 = blockIdx.y * 16, x0 = blockIdx.x * 16;
  const int tx = threadIdx.x, ty = threadIdx.y;
  const int tid = ty * 16 + tx;

  for (int px = tid; px < NPX; px += 256) {
    int ry = px / TX;
    int gy = y0 - P + ry;
    int gx = x0 - P + (px - ry * TX);
    uint4 v0, v1, v2, v3;
    if ((unsigned)gy < (unsigned)IMG && (unsigned)gx < (unsigned)IMG) {
      const uint4* sp = (const uint4*)(kn + ((size_t)b * HW + gy * IMG + gx) * 16);
      v0 = sp[0]; v1 = sp[1]; v2 = sp[2]; v3 = sp[3];
    } else {
      v0 = make_uint4(0u, 0u, 0u, 0u); v1 = v0; v2 = v0; v3 = v0;
    }
    unsigned* d = ksh + px * LS;
    d[0] = v0.x;  d[1] = v0.y;  d[2] = v0.z;  d[3] = v0.w;
    d[4] = v1.x;  d[5] = v1.y;  d[6] = v1.z;  d[7] = v1.w;
    d[8] = v2.x;  d[9] = v2.y;  d[10] = v2.z; d[11] = v2.w;
    d[12] = v3.x; d[13] = v3.y; d[14] = v3.z; d[15] = v3.w;
  }

  const int y = y0 + ty, x = x0 + tx;
  const size_t pix = (size_t)b * HW + y * IMG + x;
  float q[NA];
  {
    const uint4* sp = (const uint4*)(qn + pix * 16);
    uint4 v0 = sp[0], v1 = sp[1], v2 = sp[2], v3 = sp[3];
    unsigned u[16] = {v0.x, v0.y, v0.z, v0.w, v1.x, v1.y, v1.z, v1.w,
                      v2.x, v2.y, v2.z, v2.w, v3.x, v3.y, v3.z, v3.w};
#pragma unroll
    for (int t = 0; t < 16; ++t) { q[2 * t] = bflo(u[t]); q[2 * t + 1] = bfhi(u[t]); }
  }

  float kap = kappa[((size_t)(b * 3 + i)) * HW + y * IMG + x];
  float kmin = __uint_as_float(mm[i]);
  float kmax = __uint_as_float(mm[i + 3]);
  float kapn = (kap - kmin) / (kmax - kmin + 1e-6f);
  float tau = fminf(fmaxf(0.5f - kapn * (0.5f - 0.03f), 0.03f), 0.5f);
  float scale = 1.0f / (tau + 1e-6f);

  __syncthreads();

  float* ob = out + (size_t)b * KK * HW + y * IMG + x;
#pragma unroll 1
  for (int dy = 0; dy < KS; ++dy) {
#pragma unroll
    for (int dx = 0; dx < KS; ++dx) {
      const unsigned* kr = ksh + ((ty + dy) * TX + (tx + dx)) * LS;
      float s = 0.f;
#pragma unroll
      for (int t = 0; t < 16; ++t) {
        unsigned u = kr[t];
        s = fmaf(q[2 * t], bflo(u), s);
        s = fmaf(q[2 * t + 1], bfhi(u), s);
      }
      ob[(size_t)(dy * KS + dx) * HW] = s * scale;
    }
  }
}

// one launch covers nsl slices: blockIdx.z = sl*NB + b (block-uniform KS dispatch)
__global__ __launch_bounds__(256) void corr_all(const unsigned* __restrict__ qb,
                                                const unsigned* __restrict__ kb,
                                                const float* __restrict__ kappa,
                                                const unsigned* __restrict__ mm,
                                                const int i0, float* __restrict__ out) {
  __shared__ unsigned ksh[8228];          // 22*22*17 (KS=7 worst case)
  const int sl = blockIdx.z >> 2;
  const int b = blockIdx.z & 3;
  const int i = i0 + sl;
  const unsigned* qn = qb + (size_t)sl * NB * HW * 16;
  const unsigned* kn = kb + (size_t)sl * NB * HW * 16;
  const size_t plane = (size_t)NB * HW;
  if (i == 0)
    corr_body<3>(ksh, qn, kn, kappa, mm, 0, b, out);
  else if (i == 1)
    corr_body<5>(ksh, qn, kn, kappa, mm, 1, b, out + plane * 9);
  else
    corr_body<7>(ksh, qn, kn, kappa, mm, 2, b, out + plane * 34);
}

// ---------- launch ----------
extern "C" void kernel_launch(void* const* d_in, const int* in_sizes, int n_in,
                              void* d_out, int out_size, void* d_ws, size_t ws_size,
                              hipStream_t stream) {
  const float* feat  = (const float*)d_in[0];
  const float* kappa = (const float*)d_in[1];
  const float* qw    = (const float*)d_in[2];
  const float* kw    = (const float*)d_in[3];
  float* out = (float*)d_out;

  char* ws = (char*)d_ws;
  unsigned* mm = (unsigned*)ws;                      // 6 uints: min[3], max[3]
  unsigned short* afrag = (unsigned short*)(ws + 64);// 24576 bf16 (49 KB)
  unsigned* qbuf = (unsigned*)(ws + 65536);

  const size_t slot = (size_t)NB * HW * 16;          // uints per slice buffer (16.78 MB)
  const size_t need3 = 65536 + (size_t)6 * slot * 4; // fused: 3 slices x {q,k}
  const int fused = (ws_size >= need3) ? 1 : 0;
  const int nsl = fused ? 3 : 1;
  unsigned* kbuf = qbuf + (size_t)nsl * slot;

  hipLaunchKernelGGL(prep_afrag, dim3(96), dim3(256), 0, stream, qw, kw, afrag, mm);
  hipLaunchKernelGGL(minmax_k, dim3(64, 3), dim3(256), 0, stream, kappa, mm);

  if (fused) {
    hipLaunchKernelGGL(proj_all, dim3(NB * HW / 128), dim3(256), 0, stream,
                       feat, afrag, qbuf, kbuf, 3, 0);
    hipLaunchKernelGGL(corr_all, dim3(IMG / 16, IMG / 16, NB * 3), dim3(16, 16), 0, stream,
                       qbuf, kbuf, kappa, mm, 0, out);
  } else {
    for (int i = 0; i < 3; ++i) {
      hipLaunchKernelGGL(proj_all, dim3(NB * HW / 128), dim3(256), 0, stream,
                         feat, afrag, qbuf, kbuf, 1, i);
      hipLaunchKernelGGL(corr_all, dim3(IMG / 16, IMG / 16, NB), dim3(16, 16), 0, stream,
                         qbuf, kbuf, kappa, mm, i, out);
    }
  }
}